// Round 1
// baseline (1667.201 us; speedup 1.0000x reference)
//
#include <hip/hip_runtime.h>
#include <hip/hip_bf16.h>
#include <cstdint>
#include <cstddef>

#define B_   8192
#define DX_  512
#define DZ_  1024
#define DY_  256
#define T_   4
#define NN_  6

typedef float f32x4 __attribute__((ext_vector_type(4)));
typedef short s16x8 __attribute__((ext_vector_type(8)));
typedef __hip_bfloat16 bf16;

__device__ __forceinline__ void gload_lds16(const bf16* g, void* l) {
  __builtin_amdgcn_global_load_lds(
      (const __attribute__((address_space(1))) void*)g,
      (__attribute__((address_space(3))) void*)l,
      16, 0, 0);
}

__global__ void cvt_bf16_kernel(const float* __restrict__ in, bf16* __restrict__ out, int n4) {
  int i = blockIdx.x * blockDim.x + threadIdx.x;
  if (i >= n4) return;
  float4 v = ((const float4*)in)[i];
  ushort4 o;
  bf16 a0 = __float2bfloat16(v.x); o.x = *(unsigned short*)&a0;
  bf16 a1 = __float2bfloat16(v.y); o.y = *(unsigned short*)&a1;
  bf16 a2 = __float2bfloat16(v.z); o.z = *(unsigned short*)&a2;
  bf16 a3 = __float2bfloat16(v.w); o.w = *(unsigned short*)&a3;
  ((ushort4*)out)[i] = o;
}

// C[m,n] = act( sum_k A[m,k]*W[n,k] + bias[n] (+add1[m,n]) ), optional pre-add1 fp32 copy.
// A: [M,K] bf16 row-major (lda), W: [N,K] bf16 row-major (ldw). Tile 128x128, BK=32.
// 4 waves as 2x2, each wave 64x64 = 4x4 frags of 16x16x32 MFMA.
template<int ACT, bool OBF16>   // ACT: 0 none, 1 tanh, 2 sigmoid
__global__ __launch_bounds__(256, 2)
void gemm_bt(const bf16* __restrict__ A, int lda,
             const bf16* __restrict__ W, int ldw,
             const float* __restrict__ bias,
             const float* __restrict__ add1,
             float* __restrict__ out_pre,
             void* __restrict__ out,
             int N, int K)
{
  __shared__ bf16 lsA[128 * 32];
  __shared__ bf16 lsB[128 * 32];
  const int t    = threadIdx.x;
  const int lane = t & 63;
  const int wave = t >> 6;
  const int m0 = blockIdx.x * 128;
  const int n0 = blockIdx.y * 128;

  // staging: thread t covers row t/4 (+64 on second issue), k-chunk (t%4)*8, 16B each
  const int rA = t >> 2;
  const int c8 = (t & 3) * 8;
  const bf16* pA0 = A + (size_t)(m0 + rA) * lda + c8;
  const bf16* pA1 = pA0 + (size_t)64 * lda;
  const bf16* pB0 = W + (size_t)(n0 + rA) * ldw + c8;
  const bf16* pB1 = pB0 + (size_t)64 * ldw;
  char* lA = (char*)lsA;
  char* lB = (char*)lsB;
  const int wbyte = wave * 1024;   // wave-uniform LDS base (HW adds lane*16)

  f32x4 acc[4][4] = {};

  const int mo = (wave >> 1) * 64;
  const int no = (wave & 1) * 64;
  const int lr = lane & 15;          // fragment row (A) / col (B)
  const int kg = (lane >> 4) * 8;    // k sub-offset

  for (int kt = 0; kt < K; kt += 32) {
    gload_lds16(pA0 + kt, lA + wbyte);
    gload_lds16(pA1 + kt, lA + 4096 + wbyte);
    gload_lds16(pB0 + kt, lB + wbyte);
    gload_lds16(pB1 + kt, lB + 4096 + wbyte);
    __syncthreads();

    s16x8 af[4], bfr[4];
#pragma unroll
    for (int f = 0; f < 4; f++) {
      af[f]  = *(const s16x8*)(lsA + (mo + f * 16 + lr) * 32 + kg);
      bfr[f] = *(const s16x8*)(lsB + (no + f * 16 + lr) * 32 + kg);
    }
#pragma unroll
    for (int i = 0; i < 4; i++)
#pragma unroll
      for (int j = 0; j < 4; j++)
        acc[i][j] = __builtin_amdgcn_mfma_f32_16x16x32_bf16(af[i], bfr[j], acc[i][j], 0, 0, 0);
    __syncthreads();
  }

  // C/D layout: col = lane&15, row = (lane>>4)*4 + reg
  const int rb = (lane >> 4) * 4;
#pragma unroll
  for (int i = 0; i < 4; i++) {
#pragma unroll
    for (int j = 0; j < 4; j++) {
      const int n = n0 + no + j * 16 + lr;
      float bv = bias ? bias[n] : 0.f;
#pragma unroll
      for (int r = 0; r < 4; r++) {
        const int m = m0 + mo + i * 16 + rb + r;
        const size_t idx = (size_t)m * N + n;
        float v = acc[i][j][r] + bv;
        if (out_pre) out_pre[idx] = v;
        if (add1) v += add1[idx];
        if (ACT == 1) v = tanhf(v);
        else if (ACT == 2) v = 1.f / (1.f + __expf(-v));
        if (OBF16) ((bf16*)out)[idx] = __float2bfloat16(v);
        else ((float*)out)[idx] = v;
      }
    }
  }
}

extern "C" void kernel_launch(void* const* d_in, const int* in_sizes, int n_in,
                              void* d_out, int out_size, void* d_ws, size_t ws_size,
                              hipStream_t stream) {
  const float* xs  = (const float*)d_in[0];
  const float* Wx  = (const float*)d_in[1];
  const float* bx  = (const float*)d_in[2];
  const float* Wy  = (const float*)d_in[3];
  const float* by  = (const float*)d_in[4];
  const float* Wn  = (const float*)d_in[5];
  const float* bn  = (const float*)d_in[6];
  const float* Wu  = (const float*)d_in[7];
  const float* bu  = (const float*)d_in[8];
  const float* Wq  = (const float*)d_in[9];
  const float* bq  = (const float*)d_in[10];
  const float* ys0 = (const float*)d_in[11];
  const float* zs0 = (const float*)d_in[12];
  // T=4, n=6 fixed (reference constants)

  char* ws = (char*)d_ws;
  size_t off = 0;
  auto take = [&](size_t bytes) -> char* {
    char* p = ws + off;
    off += (bytes + 255) & ~(size_t)255;
    return p;
  };

  bf16* Wn_b = (bf16*)take((size_t)DZ_ * 3 * DZ_ * 2);
  bf16* Wx_b = (bf16*)take((size_t)DZ_ * DX_ * 2);
  bf16* Wy_b = (bf16*)take((size_t)DZ_ * DY_ * 2);
  bf16* Wu_b = (bf16*)take((size_t)DY_ * DZ_ * 2);
  bf16* Wq_b = (bf16*)take((size_t)DY_ * DZ_ * 2);
  bf16* ys_b = (bf16*)take((size_t)B_ * DZ_ * 2);
  bf16* z_a  = (bf16*)take((size_t)B_ * DZ_ * 2);
  bf16* z_b  = (bf16*)take((size_t)B_ * DZ_ * 2);
  float* cx  = (float*)take((size_t)B_ * DZ_ * 4);
  float* cy  = (float*)take((size_t)B_ * DZ_ * 4);
  float* c   = (float*)take((size_t)B_ * DZ_ * 4);
  // aliases into regions not yet written at time of use:
  bf16* xs_b   = (bf16*)c;                                  // dead before c is first written
  bf16* ysin_b = (bf16*)((char*)c + (size_t)B_ * DX_ * 2);  // ditto
  bf16* xse_b  = (bf16*)cy;                                 // dead before cy is first written

  auto cvt = [&](const float* src, bf16* dst, size_t n) {
    int n4 = (int)(n / 4);
    cvt_bf16_kernel<<<(n4 + 255) / 256, 256, 0, stream>>>(src, dst, n4);
  };
  cvt(Wn, Wn_b, (size_t)DZ_ * 3 * DZ_);
  cvt(Wx, Wx_b, (size_t)DZ_ * DX_);
  cvt(Wy, Wy_b, (size_t)DZ_ * DY_);
  cvt(Wu, Wu_b, (size_t)DY_ * DZ_);
  cvt(Wq, Wq_b, (size_t)DY_ * DZ_);
  cvt(xs, xs_b, (size_t)B_ * DX_);
  cvt(ys0, ysin_b, (size_t)B_ * DY_);
  cvt(zs0, z_a, (size_t)B_ * DZ_);

  const dim3 blk(256);
  const dim3 gz(B_ / 128, DZ_ / 128);
  const dim3 gy(B_ / 128, DY_ / 128);

  // xs_e = xs@Wx.T + bx  (bf16)
  gemm_bt<0, true><<<gz, blk, 0, stream>>>(xs_b, DX_, Wx_b, DX_, bx, nullptr, nullptr, xse_b, DZ_, DX_);
  // ys_e = ys0@Wy.T + by (bf16)
  gemm_bt<0, true><<<gz, blk, 0, stream>>>(ysin_b, DY_, Wy_b, DY_, by, nullptr, nullptr, ys_b, DZ_, DY_);
  // cx = xs_e@Wnx.T (fp32)
  gemm_bt<0, false><<<gz, blk, 0, stream>>>(xse_b, DZ_, Wn_b, 3 * DZ_, nullptr, nullptr, nullptr, cx, DZ_, DZ_);

  bf16* zc = z_a;
  bf16* zn = z_b;
  for (int tt = 0; tt < T_; ++tt) {
    // cy = ys_e@Wny.T + bn ; c = cy + cx   (both fp32, one GEMM)
    gemm_bt<0, false><<<gz, blk, 0, stream>>>(ys_b, DZ_, Wn_b + DZ_, 3 * DZ_, bn, cx, cy, c, DZ_, DZ_);
    for (int i = 0; i < NN_; ++i) {
      // z = tanh(c + z@Wnz.T)
      gemm_bt<1, true><<<gz, blk, 0, stream>>>(zc, DZ_, Wn_b + 2 * DZ_, 3 * DZ_, nullptr, c, nullptr, zn, DZ_, DZ_);
      bf16* tmp = zc; zc = zn; zn = tmp;
    }
    // ys_e = tanh(cy + z@Wnz.T)
    gemm_bt<1, true><<<gz, blk, 0, stream>>>(zc, DZ_, Wn_b + 2 * DZ_, 3 * DZ_, nullptr, cy, nullptr, ys_b, DZ_, DZ_);
  }

  float* outp = (float*)d_out;
  // y_hat = sigmoid(ys_e@Wu.T + bu), q_hat = sigmoid(ys_e@Wq.T + bq)
  gemm_bt<2, false><<<gy, blk, 0, stream>>>(ys_b, DZ_, Wu_b, DZ_, bu, nullptr, nullptr, outp, DY_, DZ_);
  gemm_bt<2, false><<<gy, blk, 0, stream>>>(ys_b, DZ_, Wq_b, DZ_, bq, nullptr, nullptr, outp + (size_t)B_ * DY_, DY_, DZ_);
}

// Round 2
// 1440.145 us; speedup vs baseline: 1.1577x; 1.1577x over previous
//
#include <hip/hip_runtime.h>
#include <hip/hip_bf16.h>
#include <cstdint>
#include <cstddef>

#define B_   8192
#define DX_  512
#define DZ_  1024
#define DY_  256
#define T_   4
#define NN_  6

typedef float f32x4 __attribute__((ext_vector_type(4)));
typedef short s16x8 __attribute__((ext_vector_type(8)));
typedef __hip_bfloat16 bf16;

__device__ __forceinline__ void gload_lds16(const bf16* g, void* l) {
  __builtin_amdgcn_global_load_lds(
      (const __attribute__((address_space(1))) void*)g,
      (__attribute__((address_space(3))) void*)l,
      16, 0, 0);
}

__global__ void cvt_bf16_kernel(const float* __restrict__ in, bf16* __restrict__ out, int n4) {
  int i = blockIdx.x * blockDim.x + threadIdx.x;
  if (i >= n4) return;
  float4 v = ((const float4*)in)[i];
  ushort4 o;
  bf16 a0 = __float2bfloat16(v.x); o.x = *(unsigned short*)&a0;
  bf16 a1 = __float2bfloat16(v.y); o.y = *(unsigned short*)&a1;
  bf16 a2 = __float2bfloat16(v.z); o.z = *(unsigned short*)&a2;
  bf16 a3 = __float2bfloat16(v.w); o.w = *(unsigned short*)&a3;
  ((ushort4*)out)[i] = o;
}

// C[m,n] = act( sum_k A[m,k]*W[n,k] + bias[n] (+add1[m,n]) ), optional pre-add1 fp32 copy.
// Tile 128x128, BK=64, double-buffered LDS, 2-phase prefetch (raw s_barrier + counted vmcnt),
// chunk-XOR LDS swizzle (linear gload_lds dest + permuted global source + XOR'd read).
// 4 waves as 2x2, each wave 64x64 = 4x4 frags of 16x16x32 MFMA.
template<int ACT, bool OBF16>   // ACT: 0 none, 1 tanh, 2 sigmoid
__global__ __launch_bounds__(256, 2)
void gemm_bt(const bf16* __restrict__ A, int lda,
             const bf16* __restrict__ W, int ldw,
             const float* __restrict__ bias,
             const float* __restrict__ add1,
             float* __restrict__ out_pre,
             void* __restrict__ out,
             int N, int K)
{
  // [buf][A/B][128 rows][64 k] bf16 : 2*2*16KB = 64KB
  __shared__ bf16 lds[2][2][128 * 64];
  const int t    = threadIdx.x;
  const int lane = t & 63;
  const int wave = t >> 6;
  const int m0 = blockIdx.x * 128;
  const int n0 = blockIdx.y * 128;

  // ---- staging: thread t stages LDS 16B-unit (issue*256 + t).
  // unit u = row*8 + pos; pos = chunk ^ (row&7)  => global chunk q = (t&7) ^ ((t>>3)&7)
  const int rr = t >> 3;                 // 0..31 (+32 per issue)
  const int qq = (t & 7) ^ (rr & 7);     // permuted 16B chunk within the 128B k-slab
  const bf16* gA = A + (size_t)(m0 + rr) * lda + qq * 8;
  const bf16* gB = W + (size_t)(n0 + rr) * ldw + qq * 8;

  char* ldsc = (char*)lds;
  const int wb = wave * 1024;            // wave-uniform part of LDS dest

  auto stage = [&](int ktel, int buf) {
    char* base = ldsc + buf * 32768;
#pragma unroll
    for (int i = 0; i < 4; ++i) {
      gload_lds16(gA + (size_t)(i * 32) * lda + ktel, base + i * 4096 + wb);
      gload_lds16(gB + (size_t)(i * 32) * ldw + ktel, base + 16384 + i * 4096 + wb);
    }
  };

  // ---- fragment read addressing
  const int mo = (wave >> 1) * 64;
  const int no = (wave & 1) * 64;
  const int fr = lane & 15;              // fragment row (A) / col (B)
  const int g4 = lane >> 4;              // k sub-chunk 0..3
  const int sx = fr & 7;                 // read-side XOR key (row&7 == fr&7)

  f32x4 acc[4][4] = {};

  const int NT = K >> 6;                 // K-tiles of 64
  stage(0, 0);

  for (int kt = 0; kt < NT; ++kt) {
    if (kt + 1 < NT) {
      stage((kt + 1) << 6, (kt + 1) & 1);
      asm volatile("s_waitcnt vmcnt(8)" ::: "memory");   // tile-kt loads landed
    } else {
      asm volatile("s_waitcnt vmcnt(0)" ::: "memory");
    }
    __builtin_amdgcn_s_barrier();
    __builtin_amdgcn_sched_barrier(0);

    const char* bA = ldsc + (kt & 1) * 32768;
    const char* bB = bA + 16384;

    s16x8 af[2][4], bf[2][4];
#pragma unroll
    for (int h = 0; h < 2; ++h) {
#pragma unroll
      for (int f = 0; f < 4; ++f) {
        const int swz = ((h * 4 + g4) ^ sx) * 16;
        af[h][f] = *(const s16x8*)(bA + (mo + f * 16 + fr) * 128 + swz);
        bf[h][f] = *(const s16x8*)(bB + (no + f * 16 + fr) * 128 + swz);
      }
    }
#pragma unroll
    for (int h = 0; h < 2; ++h)
#pragma unroll
      for (int i = 0; i < 4; ++i)
#pragma unroll
        for (int j = 0; j < 4; ++j)
          acc[i][j] = __builtin_amdgcn_mfma_f32_16x16x32_bf16(af[h][i], bf[h][j], acc[i][j], 0, 0, 0);

    __builtin_amdgcn_sched_barrier(0);
    __builtin_amdgcn_s_barrier();        // reads done before next iter's stage overwrites
  }

  // ---- epilogue.  C/D layout: col = lane&15, row = (lane>>4)*4 + reg
  const int rb = (lane >> 4) * 4;
#pragma unroll
  for (int i = 0; i < 4; i++) {
#pragma unroll
    for (int j = 0; j < 4; j++) {
      const int n = n0 + no + j * 16 + fr;
      float bv = bias ? bias[n] : 0.f;
#pragma unroll
      for (int r = 0; r < 4; r++) {
        const int m = m0 + mo + i * 16 + rb + r;
        const size_t idx = (size_t)m * N + n;
        float v = acc[i][j][r] + bv;
        if (out_pre) out_pre[idx] = v;
        if (add1) v += add1[idx];
        if (ACT == 1) v = tanhf(v);
        else if (ACT == 2) v = 1.f / (1.f + __expf(-v));
        if (OBF16) ((bf16*)out)[idx] = __float2bfloat16(v);
        else ((float*)out)[idx] = v;
      }
    }
  }
}

extern "C" void kernel_launch(void* const* d_in, const int* in_sizes, int n_in,
                              void* d_out, int out_size, void* d_ws, size_t ws_size,
                              hipStream_t stream) {
  const float* xs  = (const float*)d_in[0];
  const float* Wx  = (const float*)d_in[1];
  const float* bx  = (const float*)d_in[2];
  const float* Wy  = (const float*)d_in[3];
  const float* by  = (const float*)d_in[4];
  const float* Wn  = (const float*)d_in[5];
  const float* bn  = (const float*)d_in[6];
  const float* Wu  = (const float*)d_in[7];
  const float* bu  = (const float*)d_in[8];
  const float* Wq  = (const float*)d_in[9];
  const float* bq  = (const float*)d_in[10];
  const float* ys0 = (const float*)d_in[11];
  const float* zs0 = (const float*)d_in[12];
  // T=4, n=6 fixed (reference constants)

  char* ws = (char*)d_ws;
  size_t off = 0;
  auto take = [&](size_t bytes) -> char* {
    char* p = ws + off;
    off += (bytes + 255) & ~(size_t)255;
    return p;
  };

  bf16* Wn_b = (bf16*)take((size_t)DZ_ * 3 * DZ_ * 2);
  bf16* Wx_b = (bf16*)take((size_t)DZ_ * DX_ * 2);
  bf16* Wy_b = (bf16*)take((size_t)DZ_ * DY_ * 2);
  bf16* Wu_b = (bf16*)take((size_t)DY_ * DZ_ * 2);
  bf16* Wq_b = (bf16*)take((size_t)DY_ * DZ_ * 2);
  bf16* ys_b = (bf16*)take((size_t)B_ * DZ_ * 2);
  bf16* z_a  = (bf16*)take((size_t)B_ * DZ_ * 2);
  bf16* z_b  = (bf16*)take((size_t)B_ * DZ_ * 2);
  float* cx  = (float*)take((size_t)B_ * DZ_ * 4);
  float* cy  = (float*)take((size_t)B_ * DZ_ * 4);
  float* c   = (float*)take((size_t)B_ * DZ_ * 4);
  // aliases into regions not yet written at time of use:
  bf16* xs_b   = (bf16*)c;                                  // dead before c is first written
  bf16* ysin_b = (bf16*)((char*)c + (size_t)B_ * DX_ * 2);  // ditto
  bf16* xse_b  = (bf16*)cy;                                 // dead before cy is first written

  auto cvt = [&](const float* src, bf16* dst, size_t n) {
    int n4 = (int)(n / 4);
    cvt_bf16_kernel<<<(n4 + 255) / 256, 256, 0, stream>>>(src, dst, n4);
  };
  cvt(Wn, Wn_b, (size_t)DZ_ * 3 * DZ_);
  cvt(Wx, Wx_b, (size_t)DZ_ * DX_);
  cvt(Wy, Wy_b, (size_t)DZ_ * DY_);
  cvt(Wu, Wu_b, (size_t)DY_ * DZ_);
  cvt(Wq, Wq_b, (size_t)DY_ * DZ_);
  cvt(xs, xs_b, (size_t)B_ * DX_);
  cvt(ys0, ysin_b, (size_t)B_ * DY_);
  cvt(zs0, z_a, (size_t)B_ * DZ_);

  const dim3 blk(256);
  const dim3 gz(B_ / 128, DZ_ / 128);
  const dim3 gy(B_ / 128, DY_ / 128);

  // xs_e = xs@Wx.T + bx  (bf16)
  gemm_bt<0, true><<<gz, blk, 0, stream>>>(xs_b, DX_, Wx_b, DX_, bx, nullptr, nullptr, xse_b, DZ_, DX_);
  // ys_e = ys0@Wy.T + by (bf16)
  gemm_bt<0, true><<<gz, blk, 0, stream>>>(ysin_b, DY_, Wy_b, DY_, by, nullptr, nullptr, ys_b, DZ_, DY_);
  // cx = xs_e@Wnx.T (fp32)
  gemm_bt<0, false><<<gz, blk, 0, stream>>>(xse_b, DZ_, Wn_b, 3 * DZ_, nullptr, nullptr, nullptr, cx, DZ_, DZ_);

  bf16* zc = z_a;
  bf16* zn = z_b;
  for (int tt = 0; tt < T_; ++tt) {
    // cy = ys_e@Wny.T + bn ; c = cy + cx   (both fp32, one GEMM)
    gemm_bt<0, false><<<gz, blk, 0, stream>>>(ys_b, DZ_, Wn_b + DZ_, 3 * DZ_, bn, cx, cy, c, DZ_, DZ_);
    for (int i = 0; i < NN_; ++i) {
      // z = tanh(c + z@Wnz.T)
      gemm_bt<1, true><<<gz, blk, 0, stream>>>(zc, DZ_, Wn_b + 2 * DZ_, 3 * DZ_, nullptr, c, nullptr, zn, DZ_, DZ_);
      bf16* tmp = zc; zc = zn; zn = tmp;
    }
    // ys_e = tanh(cy + z@Wnz.T)
    gemm_bt<1, true><<<gz, blk, 0, stream>>>(zc, DZ_, Wn_b + 2 * DZ_, 3 * DZ_, nullptr, cy, nullptr, ys_b, DZ_, DZ_);
  }

  float* outp = (float*)d_out;
  // y_hat = sigmoid(ys_e@Wu.T + bu), q_hat = sigmoid(ys_e@Wq.T + bq)
  gemm_bt<2, false><<<gy, blk, 0, stream>>>(ys_b, DZ_, Wu_b, DZ_, bu, nullptr, nullptr, outp, DY_, DZ_);
  gemm_bt<2, false><<<gy, blk, 0, stream>>>(ys_b, DZ_, Wq_b, DZ_, bq, nullptr, nullptr, outp + (size_t)B_ * DY_, DY_, DZ_);
}

// Round 3
// 1206.669 us; speedup vs baseline: 1.3817x; 1.1935x over previous
//
#include <hip/hip_runtime.h>
#include <hip/hip_bf16.h>
#include <cstdint>
#include <cstddef>

#define B_   8192
#define DX_  512
#define DZ_  1024
#define DY_  256
#define T_   4
#define NN_  6

typedef float f32x4 __attribute__((ext_vector_type(4)));
typedef short s16x8 __attribute__((ext_vector_type(8)));
typedef __hip_bfloat16 bf16;

__device__ __forceinline__ void gload_lds16(const bf16* g, void* l) {
  __builtin_amdgcn_global_load_lds(
      (const __attribute__((address_space(1))) void*)g,
      (__attribute__((address_space(3))) void*)l,
      16, 0, 0);
}

__global__ void cvt_bf16_kernel(const float* __restrict__ in, bf16* __restrict__ out, int n4) {
  int i = blockIdx.x * blockDim.x + threadIdx.x;
  if (i >= n4) return;
  float4 v = ((const float4*)in)[i];
  ushort4 o;
  bf16 a0 = __float2bfloat16(v.x); o.x = *(unsigned short*)&a0;
  bf16 a1 = __float2bfloat16(v.y); o.y = *(unsigned short*)&a1;
  bf16 a2 = __float2bfloat16(v.z); o.z = *(unsigned short*)&a2;
  bf16 a3 = __float2bfloat16(v.w); o.w = *(unsigned short*)&a3;
  ((ushort4*)out)[i] = o;
}

// C[m,n] = act( sum_k A[m,k]*W[n,k] + bias[n] (+add1[m,n]) ), optional pre-add1 fp32 copy.
// Tile 128x128, BK=32, 4-deep LDS rotation, depth-2 prefetch (counted vmcnt, single
// raw s_barrier per iter), chunk-XOR swizzle (linear gload_lds dest + permuted global
// source + same XOR on read). 8 waves as 2Mx4N, wave-tile 64x32 (4x2 frags 16x16x32).
template<int ACT, bool OBF16>   // ACT: 0 none, 1 tanh, 2 sigmoid
__global__ __launch_bounds__(512, 4)
void gemm_bt(const bf16* __restrict__ A, int lda,
             const bf16* __restrict__ W, int ldw,
             const float* __restrict__ bias,
             const float* __restrict__ add1,
             float* __restrict__ out_pre,
             void* __restrict__ out,
             int N, int K)
{
  // [buf][A/B][128 rows][32 k] bf16 : 4*2*8KB = 64KB
  __shared__ bf16 lds[4][2][128 * 32];
  const int t    = threadIdx.x;
  const int lane = t & 63;
  const int wave = t >> 6;
  const int m0 = blockIdx.x * 128;
  const int n0 = blockIdx.y * 128;

  // ---- staging: thread t stages one 16B unit of A and one of B per tile.
  // LDS unit u = t = row*4 + pos; global chunk q = pos ^ ((row>>1)&3)
  const int srow = t >> 2;                     // 0..127
  const int q    = (t & 3) ^ ((t >> 3) & 3);   // source-permuted 16B chunk
  const bf16* gA = A + (size_t)(m0 + srow) * lda + q * 8;
  const bf16* gB = W + (size_t)(n0 + srow) * ldw + q * 8;

  char* ldsc = (char*)lds;
  const int wb = wave * 1024;                  // wave-uniform LDS dest base

  auto stage = [&](int ktel, int buf) {
    char* base = ldsc + buf * 16384;
    gload_lds16(gA + ktel, base + wb);
    gload_lds16(gB + ktel, base + 8192 + wb);
  };

  // ---- fragment read addressing (wave-tile 64x32: wr = wave>>2, wc = wave&3)
  const int mo = (wave >> 2) * 64;
  const int no = (wave & 3) * 32;
  const int fr = lane & 15;                    // fragment row (A) / col (B)
  const int g4 = lane >> 4;                    // k sub-chunk 0..3
  const int kx = (g4 ^ ((fr >> 1) & 3)) * 16;  // swizzled 16B chunk byte offset

  f32x4 acc[4][2] = {};

  const int NT = K >> 5;                       // K-tiles of 32 (>= 8 for all our shapes)
  stage(0, 0);
  stage(32, 1);

  for (int kt = 0; kt < NT; ++kt) {
    if (kt + 2 < NT) {
      stage((kt + 2) << 5, (kt + 2) & 3);
      asm volatile("s_waitcnt vmcnt(4)" ::: "memory");   // tile-kt loads landed
    } else if (kt + 1 < NT) {
      asm volatile("s_waitcnt vmcnt(2)" ::: "memory");
    } else {
      asm volatile("s_waitcnt vmcnt(0)" ::: "memory");
    }
    __builtin_amdgcn_s_barrier();
    __builtin_amdgcn_sched_barrier(0);

    const char* bA = ldsc + (kt & 3) * 16384;
    const char* bB = bA + 8192;

    s16x8 af[4], bf[2];
#pragma unroll
    for (int f = 0; f < 4; ++f)
      af[f] = *(const s16x8*)(bA + (mo + f * 16 + fr) * 64 + kx);
#pragma unroll
    for (int j = 0; j < 2; ++j)
      bf[j] = *(const s16x8*)(bB + (no + j * 16 + fr) * 64 + kx);

    __builtin_amdgcn_s_setprio(1);
#pragma unroll
    for (int f = 0; f < 4; ++f)
#pragma unroll
      for (int j = 0; j < 2; ++j)
        acc[f][j] = __builtin_amdgcn_mfma_f32_16x16x32_bf16(af[f], bf[j], acc[f][j], 0, 0, 0);
    __builtin_amdgcn_s_setprio(0);
  }

  // ---- epilogue.  C/D layout: col = lane&15, row = (lane>>4)*4 + reg
  const int rb = (lane >> 4) * 4;
#pragma unroll
  for (int f = 0; f < 4; f++) {
#pragma unroll
    for (int j = 0; j < 2; j++) {
      const int n = n0 + no + j * 16 + fr;
      float bv = bias ? bias[n] : 0.f;
#pragma unroll
      for (int r = 0; r < 4; r++) {
        const int m = m0 + mo + f * 16 + rb + r;
        const size_t idx = (size_t)m * N + n;
        float v = acc[f][j][r] + bv;
        if (out_pre) out_pre[idx] = v;
        if (add1) v += add1[idx];
        if (ACT == 1) { float e = __expf(2.f * v); v = 1.f - 2.f / (e + 1.f); }
        else if (ACT == 2) v = 1.f / (1.f + __expf(-v));
        if (OBF16) ((bf16*)out)[idx] = __float2bfloat16(v);
        else ((float*)out)[idx] = v;
      }
    }
  }
}

extern "C" void kernel_launch(void* const* d_in, const int* in_sizes, int n_in,
                              void* d_out, int out_size, void* d_ws, size_t ws_size,
                              hipStream_t stream) {
  const float* xs  = (const float*)d_in[0];
  const float* Wx  = (const float*)d_in[1];
  const float* bx  = (const float*)d_in[2];
  const float* Wy  = (const float*)d_in[3];
  const float* by  = (const float*)d_in[4];
  const float* Wn  = (const float*)d_in[5];
  const float* bn  = (const float*)d_in[6];
  const float* Wu  = (const float*)d_in[7];
  const float* bu  = (const float*)d_in[8];
  const float* Wq  = (const float*)d_in[9];
  const float* bq  = (const float*)d_in[10];
  const float* ys0 = (const float*)d_in[11];
  const float* zs0 = (const float*)d_in[12];
  // T=4, n=6 fixed (reference constants)

  char* ws = (char*)d_ws;
  size_t off = 0;
  auto take = [&](size_t bytes) -> char* {
    char* p = ws + off;
    off += (bytes + 255) & ~(size_t)255;
    return p;
  };

  bf16* Wn_b = (bf16*)take((size_t)DZ_ * 3 * DZ_ * 2);
  bf16* Wx_b = (bf16*)take((size_t)DZ_ * DX_ * 2);
  bf16* Wy_b = (bf16*)take((size_t)DZ_ * DY_ * 2);
  bf16* Wu_b = (bf16*)take((size_t)DY_ * DZ_ * 2);
  bf16* Wq_b = (bf16*)take((size_t)DY_ * DZ_ * 2);
  bf16* ys_b = (bf16*)take((size_t)B_ * DZ_ * 2);
  bf16* z_a  = (bf16*)take((size_t)B_ * DZ_ * 2);
  bf16* z_b  = (bf16*)take((size_t)B_ * DZ_ * 2);
  float* cx  = (float*)take((size_t)B_ * DZ_ * 4);
  float* cy  = (float*)take((size_t)B_ * DZ_ * 4);
  float* c   = (float*)take((size_t)B_ * DZ_ * 4);
  // aliases into regions not yet written at time of use:
  bf16* xs_b   = (bf16*)c;                                  // dead before c is first written
  bf16* ysin_b = (bf16*)((char*)c + (size_t)B_ * DX_ * 2);  // ditto
  bf16* xse_b  = (bf16*)cy;                                 // dead before cy is first written

  auto cvt = [&](const float* src, bf16* dst, size_t n) {
    int n4 = (int)(n / 4);
    cvt_bf16_kernel<<<(n4 + 255) / 256, 256, 0, stream>>>(src, dst, n4);
  };
  cvt(Wn, Wn_b, (size_t)DZ_ * 3 * DZ_);
  cvt(Wx, Wx_b, (size_t)DZ_ * DX_);
  cvt(Wy, Wy_b, (size_t)DZ_ * DY_);
  cvt(Wu, Wu_b, (size_t)DY_ * DZ_);
  cvt(Wq, Wq_b, (size_t)DY_ * DZ_);
  cvt(xs, xs_b, (size_t)B_ * DX_);
  cvt(ys0, ysin_b, (size_t)B_ * DY_);
  cvt(zs0, z_a, (size_t)B_ * DZ_);

  const dim3 blk(512);
  const dim3 gz(B_ / 128, DZ_ / 128);
  const dim3 gy(B_ / 128, DY_ / 128);

  // xs_e = xs@Wx.T + bx  (bf16)
  gemm_bt<0, true><<<gz, blk, 0, stream>>>(xs_b, DX_, Wx_b, DX_, bx, nullptr, nullptr, xse_b, DZ_, DX_);
  // ys_e = ys0@Wy.T + by (bf16)
  gemm_bt<0, true><<<gz, blk, 0, stream>>>(ysin_b, DY_, Wy_b, DY_, by, nullptr, nullptr, ys_b, DZ_, DY_);
  // cx = xs_e@Wnx.T (fp32)
  gemm_bt<0, false><<<gz, blk, 0, stream>>>(xse_b, DZ_, Wn_b, 3 * DZ_, nullptr, nullptr, nullptr, cx, DZ_, DZ_);

  bf16* zc = z_a;
  bf16* zn = z_b;
  for (int tt = 0; tt < T_; ++tt) {
    // cy = ys_e@Wny.T + bn ; c = cy + cx   (both fp32, one GEMM)
    gemm_bt<0, false><<<gz, blk, 0, stream>>>(ys_b, DZ_, Wn_b + DZ_, 3 * DZ_, bn, cx, cy, c, DZ_, DZ_);
    for (int i = 0; i < NN_; ++i) {
      // z = tanh(c + z@Wnz.T)
      gemm_bt<1, true><<<gz, blk, 0, stream>>>(zc, DZ_, Wn_b + 2 * DZ_, 3 * DZ_, nullptr, c, nullptr, zn, DZ_, DZ_);
      bf16* tmp = zc; zc = zn; zn = tmp;
    }
    // ys_e = tanh(cy + z@Wnz.T)
    gemm_bt<1, true><<<gz, blk, 0, stream>>>(zc, DZ_, Wn_b + 2 * DZ_, 3 * DZ_, nullptr, cy, nullptr, ys_b, DZ_, DZ_);
  }

  float* outp = (float*)d_out;
  // y_hat = sigmoid(ys_e@Wu.T + bu), q_hat = sigmoid(ys_e@Wq.T + bq)
  gemm_bt<2, false><<<gy, blk, 0, stream>>>(ys_b, DZ_, Wu_b, DZ_, bu, nullptr, nullptr, outp, DY_, DZ_);
  gemm_bt<2, false><<<gy, blk, 0, stream>>>(ys_b, DZ_, Wq_b, DZ_, bq, nullptr, nullptr, outp + (size_t)B_ * DY_, DY_, DZ_);
}

// Round 4
// 991.592 us; speedup vs baseline: 1.6813x; 1.2169x over previous
//
#include <hip/hip_runtime.h>
#include <hip/hip_bf16.h>
#include <cstdint>
#include <cstddef>

#define B_   8192
#define DX_  512
#define DZ_  1024
#define DY_  256
#define T_   4
#define NN_  6

typedef float f32x4 __attribute__((ext_vector_type(4)));
typedef short s16x8 __attribute__((ext_vector_type(8)));
typedef __hip_bfloat16 bf16;

__device__ __forceinline__ void gload_lds16(const bf16* g, void* l) {
  __builtin_amdgcn_global_load_lds(
      (const __attribute__((address_space(1))) void*)g,
      (__attribute__((address_space(3))) void*)l,
      16, 0, 0);
}

__device__ __forceinline__ float bf2f(unsigned short u) {
  union { unsigned int i; float f; } cv; cv.i = ((unsigned int)u) << 16; return cv.f;
}

__global__ void cvt_bf16_kernel(const float* __restrict__ in, bf16* __restrict__ out, int n4) {
  int i = blockIdx.x * blockDim.x + threadIdx.x;
  if (i >= n4) return;
  float4 v = ((const float4*)in)[i];
  ushort4 o;
  bf16 a0 = __float2bfloat16(v.x); o.x = *(unsigned short*)&a0;
  bf16 a1 = __float2bfloat16(v.y); o.y = *(unsigned short*)&a1;
  bf16 a2 = __float2bfloat16(v.z); o.z = *(unsigned short*)&a2;
  bf16 a3 = __float2bfloat16(v.w); o.w = *(unsigned short*)&a3;
  ((ushort4*)out)[i] = o;
}

__global__ void pack_bias_kernel(const float* __restrict__ a, const float* __restrict__ b,
                                 float* __restrict__ o) {
  int i = threadIdx.x;             // 512 threads
  o[i] = (i < DY_) ? a[i] : b[i - DY_];
}

// C[m,n] = act( preload + sum_k A[m,k]*W[n,k] ), preload = bias[n] (+ add1[m,n] unless MODE1).
// MODE: 0 = bf16 out; 1 = bf16 out_pre (pre-add1) + bf16 out (post-add1); 2 = fp32 split head.
// Block tile 128x256, BK=32, 4-buffer LDS rotation, depth-3 prefetch (counted vmcnt(6),
// single raw s_barrier/iter, stage after barrier). 8 waves as 2Mx4N, wave-tile 64x64
// (4x4 frags of 16x16x32). Chunk-XOR swizzle: linear gload_lds dest + permuted global
// source + same XOR on read (verified 0 conflicts in r2/r3).
template<int ACT, int MODE, bool HASADD>   // ACT: 0 none, 1 tanh, 2 sigmoid
__global__ __launch_bounds__(512, 2)
void gemm_bt(const bf16* __restrict__ A, int lda,
             const bf16* __restrict__ W, int ldw,
             const float* __restrict__ bias,
             const bf16* __restrict__ add1,
             bf16* __restrict__ out_pre,
             void* __restrict__ out, void* __restrict__ out2,
             int N, int K)
{
  __shared__ __align__(16) char ldsc[4 * 24576];   // [buf][A 8KB | B 16KB]
  const int t    = threadIdx.x;
  const int lane = t & 63;
  const int wave = t >> 6;
  const int m0 = blockIdx.x * 128;
  const int n0 = blockIdx.y * 256;

  // ---- staging: per tile, thread t stages 1 A-unit + 2 B-units (16B each).
  // LDS unit u: row = u>>2, pos = u&3; global chunk q = pos ^ ((row>>1)&3)
  const int rowA = t >> 2;                     // 0..127
  const int q    = (t & 3) ^ ((t >> 3) & 3);
  const bf16* gA  = A + (size_t)(m0 + rowA) * lda + q * 8;
  const bf16* gB1 = W + (size_t)(n0 + rowA) * ldw + q * 8;   // B rows 0..127
  const bf16* gB2 = gB1 + (size_t)128 * ldw;                 // B rows 128..255 (same q: 128%8==0... key=(row>>1)&3, 128>>1=64≡0 mod 4)
  const int wb = wave * 1024;                  // wave-uniform LDS dest base

  auto stage = [&](int ko, int buf) {
    char* base = ldsc + buf * 24576;
    gload_lds16(gA + ko, base + wb);
    gload_lds16(gB1 + ko, base + 8192 + wb);
    gload_lds16(gB2 + ko, base + 16384 + wb);
  };

  // ---- fragment addressing: wave (wr=wave>>2 in 0..1, wc=wave&3 in 0..3), tile 64x64
  const int mo = (wave >> 2) * 64;
  const int no = (wave & 3) * 64;
  const int fr = lane & 15;                    // fragment row (A) / col (B)
  const int g4 = lane >> 4;                    // k sub-chunk 0..3
  const int rb = g4 * 4;                       // C/D row base
  const int kx = (g4 ^ ((fr >> 1) & 3)) * 16;  // swizzled chunk byte offset

  // ---- prologue loads: bias + addend first, then the 3 staged tiles.
  float bv[4] = {0.f, 0.f, 0.f, 0.f};
  if (bias) {
#pragma unroll
    for (int j = 0; j < 4; ++j) bv[j] = bias[n0 + no + j * 16 + fr];
  }
  unsigned short adr[4][4][4];
  if (HASADD) {
#pragma unroll
    for (int f = 0; f < 4; ++f)
#pragma unroll
      for (int j = 0; j < 4; ++j) {
        const unsigned short* p = (const unsigned short*)add1
            + (size_t)(m0 + mo + f * 16 + rb) * N + (n0 + no + j * 16 + fr);
#pragma unroll
        for (int r = 0; r < 4; ++r) adr[f][j][r] = p[(size_t)r * N];
      }
  }
  __builtin_amdgcn_sched_barrier(0);           // pin prologue loads before stages
  stage(0, 0);
  stage(32, 1);
  stage(64, 2);
  __builtin_amdgcn_sched_barrier(0);

  // ---- accumulator preload (bias + addend folded in; MODE1 keeps addend for epilogue)
  f32x4 acc[4][4];
#pragma unroll
  for (int f = 0; f < 4; ++f)
#pragma unroll
    for (int j = 0; j < 4; ++j)
#pragma unroll
      for (int r = 0; r < 4; ++r) {
        float v = bv[j];
        if (HASADD && MODE != 1) v += bf2f(adr[f][j][r]);
        acc[f][j][r] = v;
      }

  const int NT = K >> 5;                       // >= 8 for all shapes used
  for (int kt = 0; kt < NT; ++kt) {
    const int rem = NT - 1 - kt;
    if (rem >= 2)      asm volatile("s_waitcnt vmcnt(6)" ::: "memory");
    else if (rem == 1) asm volatile("s_waitcnt vmcnt(3)" ::: "memory");
    else               asm volatile("s_waitcnt vmcnt(0)" ::: "memory");
    __builtin_amdgcn_s_barrier();
    __builtin_amdgcn_sched_barrier(0);
    if (kt + 3 < NT) stage((kt + 3) << 5, (kt + 3) & 3);

    const char* bA = ldsc + (kt & 3) * 24576;
    const char* bB = bA + 8192;
    s16x8 af[4], bfr[4];
#pragma unroll
    for (int f = 0; f < 4; ++f)
      af[f] = *(const s16x8*)(bA + (mo + f * 16 + fr) * 64 + kx);
#pragma unroll
    for (int j = 0; j < 4; ++j)
      bfr[j] = *(const s16x8*)(bB + (no + j * 16 + fr) * 64 + kx);

    __builtin_amdgcn_s_setprio(1);
#pragma unroll
    for (int f = 0; f < 4; ++f)
#pragma unroll
      for (int j = 0; j < 4; ++j)
        acc[f][j] = __builtin_amdgcn_mfma_f32_16x16x32_bf16(af[f], bfr[j], acc[f][j], 0, 0, 0);
    __builtin_amdgcn_s_setprio(0);
  }

  // ---- epilogue.  C/D layout: col = lane&15, row = (lane>>4)*4 + reg
#pragma unroll
  for (int f = 0; f < 4; ++f) {
#pragma unroll
    for (int j = 0; j < 4; ++j) {
      const int n = n0 + no + j * 16 + fr;
#pragma unroll
      for (int r = 0; r < 4; ++r) {
        const int m = m0 + mo + f * 16 + rb + r;
        float v = acc[f][j][r];
        if (MODE == 1) {
          out_pre[(size_t)m * N + n] = __float2bfloat16(v);
          v += bf2f(adr[f][j][r]);
        }
        if (ACT == 1)      { float e = __expf(2.f * v); v = 1.f - 2.f / (e + 1.f); }
        else if (ACT == 2) v = 1.f / (1.f + __expf(-v));
        if (MODE == 2) {
          if (n < DY_) ((float*)out)[(size_t)m * DY_ + n] = v;
          else         ((float*)out2)[(size_t)m * DY_ + (n - DY_)] = v;
        } else {
          ((bf16*)out)[(size_t)m * N + n] = __float2bfloat16(v);
        }
      }
    }
  }
}

extern "C" void kernel_launch(void* const* d_in, const int* in_sizes, int n_in,
                              void* d_out, int out_size, void* d_ws, size_t ws_size,
                              hipStream_t stream) {
  const float* xs  = (const float*)d_in[0];
  const float* Wx  = (const float*)d_in[1];
  const float* bx  = (const float*)d_in[2];
  const float* Wy  = (const float*)d_in[3];
  const float* by  = (const float*)d_in[4];
  const float* Wn  = (const float*)d_in[5];
  const float* bn  = (const float*)d_in[6];
  const float* Wu  = (const float*)d_in[7];
  const float* bu  = (const float*)d_in[8];
  const float* Wq  = (const float*)d_in[9];
  const float* bq  = (const float*)d_in[10];
  const float* ys0 = (const float*)d_in[11];
  const float* zs0 = (const float*)d_in[12];

  char* ws = (char*)d_ws;
  size_t off = 0;
  auto take = [&](size_t bytes) -> char* {
    char* p = ws + off;
    off += (bytes + 255) & ~(size_t)255;
    return p;
  };

  bf16*  Wn_b  = (bf16*)take((size_t)DZ_ * 3 * DZ_ * 2);
  bf16*  Wx_b  = (bf16*)take((size_t)DZ_ * DX_ * 2);
  bf16*  Wy_b  = (bf16*)take((size_t)DZ_ * DY_ * 2);
  bf16*  Wuq_b = (bf16*)take((size_t)2 * DY_ * DZ_ * 2);
  float* buq   = (float*)take((size_t)2 * DY_ * 4);
  bf16*  ys_b  = (bf16*)take((size_t)B_ * DZ_ * 2);
  bf16*  z_a   = (bf16*)take((size_t)B_ * DZ_ * 2);
  bf16*  z_b   = (bf16*)take((size_t)B_ * DZ_ * 2);
  bf16*  cx    = (bf16*)take((size_t)B_ * DZ_ * 2);
  bf16*  cy    = (bf16*)take((size_t)B_ * DZ_ * 2);
  bf16*  c     = (bf16*)take((size_t)B_ * DZ_ * 2);
  // aliases into regions not yet live at time of use:
  bf16* xs_b   = c;                                   // dead before c first written
  bf16* ysin_b = (bf16*)((char*)c + (size_t)B_ * DX_ * 2);  // 8.4+4.2 MB <= 16.7 MB
  bf16* xse_b  = cy;                                  // dead before cy first written

  auto cvt = [&](const float* src, bf16* dst, size_t n) {
    int n4 = (int)(n / 4);
    cvt_bf16_kernel<<<(n4 + 255) / 256, 256, 0, stream>>>(src, dst, n4);
  };
  cvt(Wn, Wn_b, (size_t)DZ_ * 3 * DZ_);
  cvt(Wx, Wx_b, (size_t)DZ_ * DX_);
  cvt(Wy, Wy_b, (size_t)DZ_ * DY_);
  cvt(Wu, Wuq_b, (size_t)DY_ * DZ_);
  cvt(Wq, Wuq_b + (size_t)DY_ * DZ_, (size_t)DY_ * DZ_);
  cvt(xs, xs_b, (size_t)B_ * DX_);
  cvt(ys0, ysin_b, (size_t)B_ * DY_);
  cvt(zs0, z_a, (size_t)B_ * DZ_);
  pack_bias_kernel<<<1, 512, 0, stream>>>(bu, bq, buq);

  const dim3 blk(512);
  const dim3 gz(B_ / 128, DZ_ / 256);   // 64 x 4
  const dim3 gh(B_ / 128, 2);           // head: N=512

  // xs_e = xs@Wx.T + bx  (bf16)
  gemm_bt<0, 0, false><<<gz, blk, 0, stream>>>(xs_b, DX_, Wx_b, DX_, bx, nullptr, nullptr, xse_b, nullptr, DZ_, DX_);
  // ys_e = ys0@Wy.T + by (bf16)
  gemm_bt<0, 0, false><<<gz, blk, 0, stream>>>(ysin_b, DY_, Wy_b, DY_, by, nullptr, nullptr, ys_b, nullptr, DZ_, DY_);
  // cx = xs_e@Wnx.T (bf16)
  gemm_bt<0, 0, false><<<gz, blk, 0, stream>>>(xse_b, DZ_, Wn_b, 3 * DZ_, nullptr, nullptr, nullptr, cx, nullptr, DZ_, DZ_);

  bf16* zc = z_a;
  bf16* zn = z_b;
  for (int tt = 0; tt < T_; ++tt) {
    // cy = ys_e@Wny.T + bn ; c = cy + cx  (both bf16, one GEMM)
    gemm_bt<0, 1, true><<<gz, blk, 0, stream>>>(ys_b, DZ_, Wn_b + DZ_, 3 * DZ_, bn, cx, cy, c, nullptr, DZ_, DZ_);
    for (int i = 0; i < NN_; ++i) {
      // z = tanh(c + z@Wnz.T)   (addend preloaded into acc)
      gemm_bt<1, 0, true><<<gz, blk, 0, stream>>>(zc, DZ_, Wn_b + 2 * DZ_, 3 * DZ_, nullptr, c, nullptr, zn, nullptr, DZ_, DZ_);
      bf16* tmp = zc; zc = zn; zn = tmp;
    }
    // ys_e = tanh(cy + z@Wnz.T)
    gemm_bt<1, 0, true><<<gz, blk, 0, stream>>>(zc, DZ_, Wn_b + 2 * DZ_, 3 * DZ_, nullptr, cy, nullptr, ys_b, nullptr, DZ_, DZ_);
  }

  float* outp = (float*)d_out;
  // y_hat | q_hat = sigmoid(ys_e@[Wu;Wq].T + [bu;bq]) — one N=512 GEMM, split store
  gemm_bt<2, 2, false><<<gh, blk, 0, stream>>>(ys_b, DZ_, Wuq_b, DZ_, buq, nullptr, nullptr,
                                               outp, outp + (size_t)B_ * DY_, 2 * DY_, DZ_);
}

// Round 5
// 984.051 us; speedup vs baseline: 1.6942x; 1.0077x over previous
//
#include <hip/hip_runtime.h>
#include <hip/hip_bf16.h>
#include <cstdint>
#include <cstddef>

#define B_   8192
#define DX_  512
#define DZ_  1024
#define DY_  256
#define T_   4
#define NN_  6

typedef float f32x4 __attribute__((ext_vector_type(4)));
typedef short s16x8 __attribute__((ext_vector_type(8)));
typedef __hip_bfloat16 bf16;

__device__ __forceinline__ void gload_lds16(const bf16* g, void* l) {
  __builtin_amdgcn_global_load_lds(
      (const __attribute__((address_space(1))) void*)g,
      (__attribute__((address_space(3))) void*)l,
      16, 0, 0);
}

__device__ __forceinline__ float bf2f(unsigned short u) {
  union { unsigned int i; float f; } cv; cv.i = ((unsigned int)u) << 16; return cv.f;
}

__global__ void cvt_bf16_kernel(const float* __restrict__ in, bf16* __restrict__ out, int n4) {
  int i = blockIdx.x * blockDim.x + threadIdx.x;
  if (i >= n4) return;
  float4 v = ((const float4*)in)[i];
  ushort4 o;
  bf16 a0 = __float2bfloat16(v.x); o.x = *(unsigned short*)&a0;
  bf16 a1 = __float2bfloat16(v.y); o.y = *(unsigned short*)&a1;
  bf16 a2 = __float2bfloat16(v.z); o.z = *(unsigned short*)&a2;
  bf16 a3 = __float2bfloat16(v.w); o.w = *(unsigned short*)&a3;
  ((ushort4*)out)[i] = o;
}

__global__ void pack_bias_kernel(const float* __restrict__ a, const float* __restrict__ b,
                                 float* __restrict__ o) {
  int i = threadIdx.x;             // 512 threads
  o[i] = (i < DY_) ? a[i] : b[i - DY_];
}

// C[m,n] = act( preload + sum_k A[m,k]*W[n,k] ), preload = bias[n] (+ add1[m,n] unless MODE1).
// MODE: 0 = bf16 out; 1 = bf16 out_pre (pre-add1) + bf16 out (post-add1); 2 = fp32 split head.
// Block tile 128x256, BK=32, 4-buffer LDS rotation, depth-3 prefetch, counted vmcnt,
// single raw s_barrier per phase. Software-pipelined LDS->reg: phase kt issues tile
// kt+1's ds_reads BEFORE tile kt's MFMA cluster (reg double-buffer, unroll-by-2,
// named frag sets — no runtime-indexed reg arrays). 8 waves as 2Mx4N, wave-tile 64x64.
// Chunk-XOR swizzle: linear gload_lds dest + permuted global source + same XOR on read
// (verified 0 bank conflicts in r2/r3).
template<int ACT, int MODE, bool HASADD>   // ACT: 0 none, 1 tanh, 2 sigmoid
__global__ __launch_bounds__(512, 2)
void gemm_bt(const bf16* __restrict__ A, int lda,
             const bf16* __restrict__ W, int ldw,
             const float* __restrict__ bias,
             const bf16* __restrict__ add1,
             bf16* __restrict__ out_pre,
             void* __restrict__ out, void* __restrict__ out2,
             int N, int K)
{
  __shared__ __align__(16) char ldsc[4 * 24576];   // [buf][A 8KB | B 16KB]
  const int t    = threadIdx.x;
  const int lane = t & 63;
  const int wave = t >> 6;
  const int m0 = blockIdx.x * 128;
  const int n0 = blockIdx.y * 256;

  // ---- staging: per tile, thread t stages 1 A-unit + 2 B-units (16B each).
  // LDS unit u: row = u>>2, pos = u&3; global chunk q = pos ^ ((row>>1)&3)
  const int rowA = t >> 2;                     // 0..127
  const int q    = (t & 3) ^ ((t >> 3) & 3);
  const bf16* gA  = A + (size_t)(m0 + rowA) * lda + q * 8;
  const bf16* gB1 = W + (size_t)(n0 + rowA) * ldw + q * 8;   // B rows 0..127
  const bf16* gB2 = gB1 + (size_t)128 * ldw;                 // B rows 128..255 (128>>1 ≡ 0 mod 4: same q)
  const int wb = wave * 1024;                  // wave-uniform LDS dest base

  auto stage = [&](int ko, int buf) {
    char* base = ldsc + buf * 24576;
    gload_lds16(gA + ko, base + wb);
    gload_lds16(gB1 + ko, base + 8192 + wb);
    gload_lds16(gB2 + ko, base + 16384 + wb);
  };

  // ---- fragment addressing: wave (wr=wave>>2 in 0..1, wc=wave&3 in 0..3), tile 64x64
  const int mo = (wave >> 2) * 64;
  const int no = (wave & 3) * 64;
  const int fr = lane & 15;                    // fragment row (A) / col (B)
  const int g4 = lane >> 4;                    // k sub-chunk 0..3
  const int rb = g4 * 4;                       // C/D row base
  const int kx = (g4 ^ ((fr >> 1) & 3)) * 16;  // swizzled chunk byte offset

  // ---- prologue loads: bias + addend first, then the 3 staged tiles.
  float bv[4] = {0.f, 0.f, 0.f, 0.f};
  if (bias) {
#pragma unroll
    for (int j = 0; j < 4; ++j) bv[j] = bias[n0 + no + j * 16 + fr];
  }
  unsigned short adr[4][4][4];
  if (HASADD) {
#pragma unroll
    for (int f = 0; f < 4; ++f)
#pragma unroll
      for (int j = 0; j < 4; ++j) {
        const unsigned short* p = (const unsigned short*)add1
            + (size_t)(m0 + mo + f * 16 + rb) * N + (n0 + no + j * 16 + fr);
#pragma unroll
        for (int r = 0; r < 4; ++r) adr[f][j][r] = p[(size_t)r * N];
      }
  }
  __builtin_amdgcn_sched_barrier(0);           // pin prologue loads before stages
  stage(0, 0);
  stage(32, 1);
  stage(64, 2);
  __builtin_amdgcn_sched_barrier(0);

  // ---- accumulator preload (bias + addend folded in; MODE1 keeps addend for epilogue)
  f32x4 acc[4][4];
#pragma unroll
  for (int f = 0; f < 4; ++f)
#pragma unroll
    for (int j = 0; j < 4; ++j)
#pragma unroll
      for (int r = 0; r < 4; ++r) {
        float v = bv[j];
        if (HASADD && MODE != 1) v += bf2f(adr[f][j][r]);
        acc[f][j][r] = v;
      }

  // ---- frag helpers (named reg sets; all indices compile-time under unroll)
  s16x8 aA[4], bA[4], aB[4], bB[4];
  auto ldfrags = [&](int kt, s16x8* fa, s16x8* fb) {
    const char* pA = ldsc + (kt & 3) * 24576;
    const char* pB = pA + 8192;
#pragma unroll
    for (int f = 0; f < 4; ++f) fa[f] = *(const s16x8*)(pA + (mo + f * 16 + fr) * 64 + kx);
#pragma unroll
    for (int j = 0; j < 4; ++j) fb[j] = *(const s16x8*)(pB + (no + j * 16 + fr) * 64 + kx);
  };
  auto domfma = [&](const s16x8* fa, const s16x8* fb) {
    __builtin_amdgcn_s_setprio(1);
#pragma unroll
    for (int f = 0; f < 4; ++f)
#pragma unroll
      for (int j = 0; j < 4; ++j)
        acc[f][j] = __builtin_amdgcn_mfma_f32_16x16x32_bf16(fa[f], fb[j], acc[f][j], 0, 0, 0);
    __builtin_amdgcn_s_setprio(0);
  };

  const int NT = K >> 5;                       // 8/16/32 here — always even, >= 4

  // ---- preloop: tile 0 ready, frags[0] in regs
  asm volatile("s_waitcnt vmcnt(6)" ::: "memory");
  __builtin_amdgcn_s_barrier();
  __builtin_amdgcn_sched_barrier(0);
  ldfrags(0, aA, bA);

  for (int kt = 0; kt < NT; kt += 2) {
    // phase 1: ensure tile kt+1 in LDS; stage kt+3; prefetch frags kt+1; compute kt
    if (kt + 2 < NT) asm volatile("s_waitcnt vmcnt(3)" ::: "memory");
    else             asm volatile("s_waitcnt vmcnt(0)" ::: "memory");
    __builtin_amdgcn_s_barrier();
    __builtin_amdgcn_sched_barrier(0);
    if (kt + 3 < NT) stage((kt + 3) << 5, (kt + 3) & 3);
    ldfrags(kt + 1, aB, bB);
    domfma(aA, bA);
    // phase 2: ensure tile kt+2 in LDS; stage kt+4; prefetch frags kt+2; compute kt+1
    if (kt + 2 < NT) {
      if (kt + 3 < NT) asm volatile("s_waitcnt vmcnt(3)" ::: "memory");
      else             asm volatile("s_waitcnt vmcnt(0)" ::: "memory");
      __builtin_amdgcn_s_barrier();
      __builtin_amdgcn_sched_barrier(0);
      if (kt + 4 < NT) stage((kt + 4) << 5, (kt + 4) & 3);
      ldfrags(kt + 2, aA, bA);
    }
    domfma(aB, bB);
  }

  // ---- epilogue.  C/D layout: col = lane&15, row = (lane>>4)*4 + reg
#pragma unroll
  for (int f = 0; f < 4; ++f) {
#pragma unroll
    for (int j = 0; j < 4; ++j) {
      const int n = n0 + no + j * 16 + fr;
#pragma unroll
      for (int r = 0; r < 4; ++r) {
        const int m = m0 + mo + f * 16 + rb + r;
        float v = acc[f][j][r];
        if (MODE == 1) {
          out_pre[(size_t)m * N + n] = __float2bfloat16(v);
          v += bf2f(adr[f][j][r]);
        }
        if (ACT == 1)      { float e = __expf(2.f * v); v = 1.f - 2.f / (e + 1.f); }
        else if (ACT == 2) v = 1.f / (1.f + __expf(-v));
        if (MODE == 2) {
          if (n < DY_) ((float*)out)[(size_t)m * DY_ + n] = v;
          else         ((float*)out2)[(size_t)m * DY_ + (n - DY_)] = v;
        } else {
          ((bf16*)out)[(size_t)m * N + n] = __float2bfloat16(v);
        }
      }
    }
  }
}

extern "C" void kernel_launch(void* const* d_in, const int* in_sizes, int n_in,
                              void* d_out, int out_size, void* d_ws, size_t ws_size,
                              hipStream_t stream) {
  const float* xs  = (const float*)d_in[0];
  const float* Wx  = (const float*)d_in[1];
  const float* bx  = (const float*)d_in[2];
  const float* Wy  = (const float*)d_in[3];
  const float* by  = (const float*)d_in[4];
  const float* Wn  = (const float*)d_in[5];
  const float* bn  = (const float*)d_in[6];
  const float* Wu  = (const float*)d_in[7];
  const float* bu  = (const float*)d_in[8];
  const float* Wq  = (const float*)d_in[9];
  const float* bq  = (const float*)d_in[10];
  const float* ys0 = (const float*)d_in[11];
  const float* zs0 = (const float*)d_in[12];

  char* ws = (char*)d_ws;
  size_t off = 0;
  auto take = [&](size_t bytes) -> char* {
    char* p = ws + off;
    off += (bytes + 255) & ~(size_t)255;
    return p;
  };

  bf16*  Wn_b  = (bf16*)take((size_t)DZ_ * 3 * DZ_ * 2);
  bf16*  Wx_b  = (bf16*)take((size_t)DZ_ * DX_ * 2);
  bf16*  Wy_b  = (bf16*)take((size_t)DZ_ * DY_ * 2);
  bf16*  Wuq_b = (bf16*)take((size_t)2 * DY_ * DZ_ * 2);
  float* buq   = (float*)take((size_t)2 * DY_ * 4);
  bf16*  ys_b  = (bf16*)take((size_t)B_ * DZ_ * 2);
  bf16*  z_a   = (bf16*)take((size_t)B_ * DZ_ * 2);
  bf16*  z_b   = (bf16*)take((size_t)B_ * DZ_ * 2);
  bf16*  cx    = (bf16*)take((size_t)B_ * DZ_ * 2);
  bf16*  cy    = (bf16*)take((size_t)B_ * DZ_ * 2);
  bf16*  c     = (bf16*)take((size_t)B_ * DZ_ * 2);
  // aliases into regions not yet live at time of use:
  bf16* xs_b   = c;                                   // dead before c first written
  bf16* ysin_b = (bf16*)((char*)c + (size_t)B_ * DX_ * 2);  // 8.4+4.2 MB <= 16.7 MB
  bf16* xse_b  = cy;                                  // dead before cy first written

  auto cvt = [&](const float* src, bf16* dst, size_t n) {
    int n4 = (int)(n / 4);
    cvt_bf16_kernel<<<(n4 + 255) / 256, 256, 0, stream>>>(src, dst, n4);
  };
  cvt(Wn, Wn_b, (size_t)DZ_ * 3 * DZ_);
  cvt(Wx, Wx_b, (size_t)DZ_ * DX_);
  cvt(Wy, Wy_b, (size_t)DZ_ * DY_);
  cvt(Wu, Wuq_b, (size_t)DY_ * DZ_);
  cvt(Wq, Wuq_b + (size_t)DY_ * DZ_, (size_t)DY_ * DZ_);
  cvt(xs, xs_b, (size_t)B_ * DX_);
  cvt(ys0, ysin_b, (size_t)B_ * DY_);
  cvt(zs0, z_a, (size_t)B_ * DZ_);
  pack_bias_kernel<<<1, 512, 0, stream>>>(bu, bq, buq);

  const dim3 blk(512);
  const dim3 gz(B_ / 128, DZ_ / 256);   // 64 x 4
  const dim3 gh(B_ / 128, 2);           // head: N=512

  // xs_e = xs@Wx.T + bx  (bf16)
  gemm_bt<0, 0, false><<<gz, blk, 0, stream>>>(xs_b, DX_, Wx_b, DX_, bx, nullptr, nullptr, xse_b, nullptr, DZ_, DX_);
  // ys_e = ys0@Wy.T + by (bf16)
  gemm_bt<0, 0, false><<<gz, blk, 0, stream>>>(ysin_b, DY_, Wy_b, DY_, by, nullptr, nullptr, ys_b, nullptr, DZ_, DY_);
  // cx = xs_e@Wnx.T (bf16)
  gemm_bt<0, 0, false><<<gz, blk, 0, stream>>>(xse_b, DZ_, Wn_b, 3 * DZ_, nullptr, nullptr, nullptr, cx, nullptr, DZ_, DZ_);

  bf16* zc = z_a;
  bf16* zn = z_b;
  for (int tt = 0; tt < T_; ++tt) {
    // cy = ys_e@Wny.T + bn ; c = cy + cx  (both bf16, one GEMM)
    gemm_bt<0, 1, true><<<gz, blk, 0, stream>>>(ys_b, DZ_, Wn_b + DZ_, 3 * DZ_, bn, cx, cy, c, nullptr, DZ_, DZ_);
    for (int i = 0; i < NN_; ++i) {
      // z = tanh(c + z@Wnz.T)   (addend preloaded into acc)
      gemm_bt<1, 0, true><<<gz, blk, 0, stream>>>(zc, DZ_, Wn_b + 2 * DZ_, 3 * DZ_, nullptr, c, nullptr, zn, nullptr, DZ_, DZ_);
      bf16* tmp = zc; zc = zn; zn = tmp;
    }
    // ys_e = tanh(cy + z@Wnz.T)
    gemm_bt<1, 0, true><<<gz, blk, 0, stream>>>(zc, DZ_, Wn_b + 2 * DZ_, 3 * DZ_, nullptr, cy, nullptr, ys_b, nullptr, DZ_, DZ_);
  }

  float* outp = (float*)d_out;
  // y_hat | q_hat = sigmoid(ys_e@[Wu;Wq].T + [bu;bq]) — one N=512 GEMM, split store
  gemm_bt<2, 2, false><<<gh, blk, 0, stream>>>(ys_b, DZ_, Wuq_b, DZ_, buq, nullptr, nullptr,
                                               outp, outp + (size_t)B_ * DY_, 2 * DY_, DZ_);
}